// Round 2
// baseline (108.571 us; speedup 1.0000x reference)
//
#include <hip/hip_runtime.h>

constexpr int NL = 256;   // lights
constexpr int HW = 256;   // H == W

__global__ __launch_bounds__(256, 4)
void lsf_kernel(const float* __restrict__ X,
                const float* __restrict__ shots,
                const float* __restrict__ lpos,
                float* __restrict__ out, int B)
{
    __shared__ float2 s_lp[NL];
    for (int i = threadIdx.x; i < NL; i += 256)
        s_lp[i] = reinterpret_cast<const float2*>(lpos)[i];
    __syncthreads();

    int b = blockIdx.x * 256 + threadIdx.x;
    if (b >= B) return;

    float4 xv = reinterpret_cast<const float4*>(X)[b];
    float qx = xv.z, qy = xv.w;   // direction coords (X[:,2:4])

    // ---- bilinear sample coords first (scan-independent) ----
    float px = fminf(fmaxf((xv.x + 1.f) * 0.5f * (HW - 1), 0.f), (float)(HW - 1));
    float py = fminf(fmaxf((xv.y + 1.f) * 0.5f * (HW - 1), 0.f), (float)(HW - 1));
    int x0 = (int)floorf(px), y0 = (int)floorf(py);
    int x1 = min(x0 + 1, HW - 1), y1 = min(y0 + 1, HW - 1);
    float wx = px - (float)x0, wy = py - (float)y0;
    float w00 = (1.f - wy) * (1.f - wx), w01 = (1.f - wy) * wx;
    float w10 = wy * (1.f - wx),         w11 = wy * wx;
    int o00 = y0 * HW + x0, o01 = y0 * HW + x1;
    int o10 = y1 * HW + x0, o11 = y1 * HW + x1;

    // ---- top-3 nearest lights (ascending distance, ties -> lower index) ----
    float d0 = INFINITY, d1 = INFINITY, d2 = INFINITY;
    int i0 = 0, i1 = 0, i2 = 0;
    #pragma unroll 8
    for (int i = 0; i < NL; ++i) {
        float2 lp = s_lp[i];
        float dx = qx - lp.x, dy = qy - lp.y;
        float d = dx * dx + dy * dy;
        if (d < d0)      { d2 = d1; i2 = i1; d1 = d0; i1 = i0; d0 = d; i0 = i; }
        else if (d < d1) { d2 = d1; i2 = i1; d1 = d;  i1 = i; }
        else if (d < d2) { d2 = d;  i2 = i; }
    }

    // ---- barycentric weights (branchless fallback) ----
    float2 p0 = s_lp[i0], p1 = s_lp[i1], p2c = s_lp[i2];
    float v0x = p1.x - p0.x,  v0y = p1.y - p0.y;
    float v1x = p2c.x - p0.x, v1y = p2c.y - p0.y;
    float v2x = qx - p0.x,    v2y = qy - p0.y;
    float d00 = v0x * v0x + v0y * v0y;
    float d11 = v1x * v1x + v1y * v1y;
    float d01 = v0x * v1x + v0y * v1y;
    float d20 = v2x * v0x + v2y * v0y;
    float d21 = v2x * v1x + v2y * v1y;
    float denom = d00 * d11 - d01 * d01;
    float v = (d11 * d20 - d01 * d21) / denom;
    float w = (d00 * d21 - d01 * d20) / denom;
    float u = 1.0f - v - w;
    // outside == !(u>=0 && v>=0 && w>=0)  (NaN fails >=)
    bool inside = (u >= 0.f) & (v >= 0.f) & (w >= 0.f);
    float t = fminf(fmaxf(d20 / d00, 0.f), 1.f);
    float w0 = inside ? u : (1.f - t);
    float w1 = inside ? v : t;
    float w2 = inside ? w : 0.f;

    // ---- gather: issue ALL 36 loads before any use (max MLP) ----
    int idx3[3] = { i0, i1, i2 };
    float g00[9], g01[9], g10[9], g11[9];
    #pragma unroll
    for (int k = 0; k < 3; ++k) {
        const float* base = shots + (size_t)idx3[k] * (3 * HW * HW);
        #pragma unroll
        for (int c = 0; c < 3; ++c) {
            const float* p = base + c * (HW * HW);
            int j = k * 3 + c;
            g00[j] = p[o00];
            g01[j] = p[o01];
            g10[j] = p[o10];
            g11[j] = p[o11];
        }
    }

    float wk3[3] = { w0, w1, w2 };
    float acc[3] = { 0.f, 0.f, 0.f };
    #pragma unroll
    for (int k = 0; k < 3; ++k) {
        #pragma unroll
        for (int c = 0; c < 3; ++c) {
            int j = k * 3 + c;
            float col = g00[j] * w00 + g01[j] * w01 +
                        g10[j] * w10 + g11[j] * w11;
            acc[c] += wk3[k] * col;
        }
    }

    out[(size_t)b * 3 + 0] = acc[0];
    out[(size_t)b * 3 + 1] = acc[1];
    out[(size_t)b * 3 + 2] = acc[2];
}

extern "C" void kernel_launch(void* const* d_in, const int* in_sizes, int n_in,
                              void* d_out, int out_size, void* d_ws, size_t ws_size,
                              hipStream_t stream) {
    const float* X     = (const float*)d_in[0];
    const float* shots = (const float*)d_in[1];
    const float* lpos  = (const float*)d_in[2];
    float* out = (float*)d_out;
    int B = in_sizes[0] / 4;
    int grid = (B + 255) / 256;
    lsf_kernel<<<grid, 256, 0, stream>>>(X, shots, lpos, out, B);
}

// Round 3
// 105.846 us; speedup vs baseline: 1.0257x; 1.0257x over previous
//
#include <hip/hip_runtime.h>

constexpr int NL = 256;   // lights
constexpr int HW = 256;   // H == W
constexpr int GS = 66;    // accel grid cells per side
constexpr int NCELL = GS * GS;
constexpr float RGRID = 4.125f;   // grid covers [-RGRID, RGRID]^2
constexpr int KCAND = 32;         // max candidates per cell

// 8-byte value with 4-byte alignment: backend may merge to dwordx2 (4B-aligned
// multi-dword global loads are legal on CDNA); else splits to 2 dwords. Both correct.
struct __attribute__((aligned(4))) F2 { float a, b; };

__global__ __launch_bounds__(256)
void build_grid(const float* __restrict__ lpos,
                unsigned char* __restrict__ cand,
                int* __restrict__ cnt)
{
    __shared__ float2 s_lp[NL];
    for (int i = threadIdx.x; i < NL; i += 256)
        s_lp[i] = reinterpret_cast<const float2*>(lpos)[i];
    __syncthreads();

    int cell = blockIdx.x * 256 + threadIdx.x;
    if (cell >= NCELL) return;
    const float CELLW = 2.f * RGRID / GS;
    float cx = -RGRID + ((cell % GS) + 0.5f) * CELLW;
    float cy = -RGRID + ((cell / GS) + 0.5f) * CELLW;

    // 3rd-smallest distance^2 from cell center (values only, bubble insert)
    float d0 = INFINITY, d1 = INFINITY, d2 = INFINITY;
    for (int i = 0; i < NL; ++i) {
        float dx = cx - s_lp[i].x, dy = cy - s_lp[i].y;
        float d = dx * dx + dy * dy;
        float n0 = fminf(d0, d), m0 = fmaxf(d0, d); d0 = n0;
        float n1 = fminf(d1, m0), m1 = fmaxf(d1, m0); d1 = n1;
        d2 = fminf(d2, m1);
    }
    // conservative bound: any in-cell query's top-3 light i satisfies
    // dist(center,i) <= d3(center) + 2*halfdiag
    float r = 0.70710678f * CELLW;
    float bnd = sqrtf(d2) + 2.f * r;
    bnd *= bnd;

    unsigned char* dst = cand + (size_t)cell * KCAND;
    int n = 0;
    for (int i = 0; i < NL; ++i) {       // ascending index -> tie-stable order
        float dx = cx - s_lp[i].x, dy = cy - s_lp[i].y;
        float d = dx * dx + dy * dy;
        if (d <= bnd) {
            if (n < KCAND) dst[n] = (unsigned char)i;
            ++n;
        }
    }
    cnt[cell] = n;   // n > KCAND => sentinel: full scan
}

template<bool USE_GRID>
__global__ __launch_bounds__(256, 4)
void lsf_kernel(const float* __restrict__ X,
                const float* __restrict__ shots,
                const float* __restrict__ lpos,
                const unsigned char* __restrict__ cand,
                const int* __restrict__ cnt,
                float* __restrict__ out, int B)
{
    __shared__ float2 s_lp[NL];
    for (int i = threadIdx.x; i < NL; i += 256)
        s_lp[i] = reinterpret_cast<const float2*>(lpos)[i];
    __syncthreads();

    int b = blockIdx.x * 256 + threadIdx.x;
    if (b >= B) return;

    float4 xv = reinterpret_cast<const float4*>(X)[b];
    float qx = xv.z, qy = xv.w;

    // ---- bilinear coords (scan-independent) ----
    float px = fminf(fmaxf((xv.x + 1.f) * 0.5f * (HW - 1), 0.f), (float)(HW - 1));
    float py = fminf(fmaxf((xv.y + 1.f) * 0.5f * (HW - 1), 0.f), (float)(HW - 1));
    int x0 = (int)floorf(px), y0 = (int)floorf(py);
    int y1 = min(y0 + 1, HW - 1);
    float wx = px - (float)x0, wy = py - (float)y0;
    float w00 = (1.f - wy) * (1.f - wx), w01 = (1.f - wy) * wx;
    float w10 = wy * (1.f - wx),         w11 = wy * wx;
    int  xe  = min(x0, HW - 2);          // pair base; border handled by select
    bool xhi = (x0 == HW - 1);

    // ---- top-3 nearest (exact compare semantics, ties -> lower index) ----
    float dd0 = INFINITY, dd1 = INFINITY, dd2 = INFINITY;
    int i0 = 0, i1 = 0, i2 = 0;
    auto visit = [&](int idx) {
        float2 lp = s_lp[idx];
        float dx = qx - lp.x, dy = qy - lp.y;
        float d = dx * dx + dy * dy;
        bool c0 = d < dd0, c1 = d < dd1, c2 = d < dd2;
        dd2 = c1 ? dd1 : (c2 ? d   : dd2);
        i2  = c1 ? i1  : (c2 ? idx : i2);
        dd1 = c0 ? dd0 : (c1 ? d   : dd1);
        i1  = c0 ? i0  : (c1 ? idx : i1);
        dd0 = c0 ? d   : dd0;
        i0  = c0 ? idx : i0;
    };

    bool full = true;
    if constexpr (USE_GRID) {
        if (fabsf(qx) <= RGRID && fabsf(qy) <= RGRID) {
            const float CELLW = 2.f * RGRID / GS;
            int cxi = min((int)((qx + RGRID) / CELLW), GS - 1);
            int cyi = min((int)((qy + RGRID) / CELLW), GS - 1);
            int cell = cyi * GS + cxi;
            int nn = cnt[cell];
            if (nn <= KCAND) {
                const uint4* lp32 =
                    reinterpret_cast<const uint4*>(cand + (size_t)cell * KCAND);
                uint4 L0 = lp32[0], L1 = lp32[1];
#define STEP(WV, BASE, BB) \
                if ((BASE) + (BB) < nn) { int ix = ((WV) >> ((BB) * 8)) & 255; visit(ix); }
#define PROCW(WV, BASE) \
                if ((BASE) < nn) { STEP(WV, BASE, 0) STEP(WV, BASE, 1) STEP(WV, BASE, 2) STEP(WV, BASE, 3) }
                PROCW(L0.x, 0)  PROCW(L0.y, 4)  PROCW(L0.z, 8)  PROCW(L0.w, 12)
                PROCW(L1.x, 16) PROCW(L1.y, 20) PROCW(L1.z, 24) PROCW(L1.w, 28)
#undef PROCW
#undef STEP
                full = false;
            }
        }
    }
    if (full) {
        #pragma unroll 4
        for (int i = 0; i < NL; ++i) visit(i);
    }

    // ---- barycentric weights (branchless fallback; NaN -> fallback) ----
    float2 p0 = s_lp[i0], p1 = s_lp[i1], p2c = s_lp[i2];
    float v0x = p1.x - p0.x,  v0y = p1.y - p0.y;
    float v1x = p2c.x - p0.x, v1y = p2c.y - p0.y;
    float v2x = qx - p0.x,    v2y = qy - p0.y;
    float d00 = v0x * v0x + v0y * v0y;
    float d11 = v1x * v1x + v1y * v1y;
    float d01 = v0x * v1x + v0y * v1y;
    float d20 = v2x * v0x + v2y * v0y;
    float d21 = v2x * v1x + v2y * v1y;
    float denom = d00 * d11 - d01 * d01;
    float v = (d11 * d20 - d01 * d21) / denom;
    float w = (d00 * d21 - d01 * d20) / denom;
    float u = 1.0f - v - w;
    bool inside = (u >= 0.f) & (v >= 0.f) & (w >= 0.f);
    float t = fminf(fmaxf(d20 / d00, 0.f), 1.f);
    float w0 = inside ? u : (1.f - t);
    float w1 = inside ? v : t;
    float w2 = inside ? w : 0.f;

    // ---- gather: 18 x-pair loads (issue all, then combine) ----
    int   idx3[3] = { i0, i1, i2 };
    float wk3[3]  = { w0, w1, w2 };
    F2 G0[9], G1[9];
    #pragma unroll
    for (int k = 0; k < 3; ++k) {
        const float* base = shots + (size_t)idx3[k] * (3 * HW * HW);
        #pragma unroll
        for (int c = 0; c < 3; ++c) {
            const float* p = base + c * (HW * HW) + xe;
            int j = k * 3 + c;
            G0[j] = *reinterpret_cast<const F2*>(p + y0 * HW);
            G1[j] = *reinterpret_cast<const F2*>(p + y1 * HW);
        }
    }

    float acc[3] = { 0.f, 0.f, 0.f };
    #pragma unroll
    for (int k = 0; k < 3; ++k) {
        #pragma unroll
        for (int c = 0; c < 3; ++c) {
            int j = k * 3 + c;
            float v00 = xhi ? G0[j].b : G0[j].a;
            float v10 = xhi ? G1[j].b : G1[j].a;
            float col = v00 * w00 + G0[j].b * w01 +
                        v10 * w10 + G1[j].b * w11;
            acc[c] += wk3[k] * col;
        }
    }

    out[(size_t)b * 3 + 0] = acc[0];
    out[(size_t)b * 3 + 1] = acc[1];
    out[(size_t)b * 3 + 2] = acc[2];
}

extern "C" void kernel_launch(void* const* d_in, const int* in_sizes, int n_in,
                              void* d_out, int out_size, void* d_ws, size_t ws_size,
                              hipStream_t stream) {
    const float* X     = (const float*)d_in[0];
    const float* shots = (const float*)d_in[1];
    const float* lpos  = (const float*)d_in[2];
    float* out = (float*)d_out;
    int B = in_sizes[0] / 4;
    int grid = (B + 255) / 256;

    size_t cand_bytes = (size_t)NCELL * KCAND;
    size_t need = cand_bytes + (size_t)NCELL * sizeof(int);
    if (ws_size >= need) {
        unsigned char* cand = (unsigned char*)d_ws;
        int* cnt = (int*)((char*)d_ws + cand_bytes);
        build_grid<<<(NCELL + 255) / 256, 256, 0, stream>>>(lpos, cand, cnt);
        lsf_kernel<true><<<grid, 256, 0, stream>>>(X, shots, lpos, cand, cnt, out, B);
    } else {
        lsf_kernel<false><<<grid, 256, 0, stream>>>(X, shots, lpos,
                                                    nullptr, nullptr, out, B);
    }
}